// Round 1
// baseline (192.316 us; speedup 1.0000x reference)
//
#include <hip/hip_runtime.h>
#include <stdint.h>

#define H 192
#define W 192
#define CIN 32
#define NOUT 32
#define NB 16
#define PADI 4
#define HP 200          // padded rows
#define WP 200          // padded cols

#define HT 16           // output rows per block
#define WTL 16          // output cols per block
#define RROWS 24        // HT + 8 halo
#define RCOLS 24        // WTL + 8 halo

typedef __attribute__((ext_vector_type(8))) short bf16x8;
typedef __attribute__((ext_vector_type(4))) float f32x4;

__device__ __forceinline__ unsigned short f2bf(float f) {
    union { float f; unsigned int u; } v; v.f = f;
    unsigned int r = v.u + 0x7fffu + ((v.u >> 16) & 1u);
    return (unsigned short)(r >> 16);
}

__device__ __forceinline__ void gload_lds16(const void* g, void* l) {
    __builtin_amdgcn_global_load_lds(
        (const __attribute__((address_space(1))) void*)g,
        (__attribute__((address_space(3))) void*)l, 16, 0, 0);
}

// ---- Gaussian kernel generation: one block per (o,i) pair, one thread per tap ----
__global__ void genw_kernel(const float* __restrict__ wp, unsigned short* __restrict__ W2g) {
    const int b = blockIdx.x;          // = o*32 + i
    const int o = b >> 5;
    const int i = b & 31;
    const int t = threadIdx.x;         // 0..127

    float sx = wp[b * 3 + 0], sy = wp[b * 3 + 1], th = wp[b * 3 + 2];
    float rad = th / 180.0f * 3.14159265358979323846f;
    float co = cosf(rad), si = sinf(rad);
    float sx2 = sx * sx, sy2 = sy * sy;
    float a = co * co * sx2 + si * si * sy2;
    float bb = co * si * (sx2 - sy2);
    float d = si * si * sx2 + co * co * sy2;
    float det = a * d - bb * bb;
    float ia = d / det, ib = -bb / det, idd = a / det;

    const int tap = t;
    float e = 0.0f;
    if (tap < 81) {
        float xx = (float)(tap % 9 - 4);
        float yy = (float)(tap / 9 - 4);
        float q = ia * xx * xx + 2.0f * ib * xx * yy + idd * yy * yy;
        e = expf(-0.5f * q);
    }
    float s = e;
    #pragma unroll
    for (int off = 32; off > 0; off >>= 1) s += __shfl_down(s, off);
    __shared__ float ws[2];
    if ((t & 63) == 0) ws[t >> 6] = s;
    __syncthreads();
    float total = ws[0] + ws[1];

    if (tap < 81) {
        int mt = o >> 4, m = o & 15, quad = i >> 3, j = i & 7;
        W2g[((((mt * 81 + tap) * 4 + quad) * 16 + m) << 3) + j] = f2bf(e / total);
    }
}

// ---- Pre-pass: NCHW fp32 -> zero-padded channel-blocked bf16 ----
// xb layout: [n][quad][rp 200][wp 200][8ch], 16B granule per (pixel, quad).
// Border granules written as zeros (covers conv's halo with no bounds checks).
__global__ __launch_bounds__(256) void xpad_kernel(
    const float* __restrict__ x, unsigned short* __restrict__ xb)
{
    const int gid = blockIdx.x * 256 + threadIdx.x;   // 0 .. 16*4*200*200-1
    const int wpix = gid % WP;
    int rest = gid / WP;
    const int rp = rest % HP;
    rest /= HP;
    const int quad = rest & 3;
    const int n = rest >> 2;

    const int row = rp - PADI;
    const int col = wpix - PADI;

    unsigned int d[4] = {0u, 0u, 0u, 0u};
    if ((unsigned)row < (unsigned)H && (unsigned)col < (unsigned)W) {
        const float* p = x + (((size_t)(n * CIN + quad * 8)) * H + row) * (size_t)W + col;
        float v[8];
        #pragma unroll
        for (int k = 0; k < 8; k++) v[k] = p[(size_t)k * H * W];
        #pragma unroll
        for (int k = 0; k < 4; k++)
            d[k] = (unsigned int)f2bf(v[2 * k]) | ((unsigned int)f2bf(v[2 * k + 1]) << 16);
    }
    *(uint4*)&xb[(size_t)gid * 8] = make_uint4(d[0], d[1], d[2], d[3]);
}

// ---- Conv kernel (fast path): staging = 9x global_load_lds_dwordx4, no VALU ----
__global__ __launch_bounds__(256, 4) void conv_kernel(
    const unsigned short* __restrict__ xb, const unsigned short* __restrict__ W2g,
    const float* __restrict__ bias, float* __restrict__ out)
{
    __shared__ __align__(16) unsigned short ldsx[4 * RROWS * RCOLS * 8];  // 36,864 B

    const int t = threadIdx.x;
    // XCD-contiguous swizzle: 8 classes x 288 tiles
    const int bid = (blockIdx.x & 7) * 288 + (blockIdx.x >> 3);
    const int wb = bid % (W / WTL);                 // 0..11
    const int hb = (bid / (W / WTL)) % (H / HT);    // 0..11
    const int n  = bid / ((W / WTL) * (H / HT));    // 0..15
    const int r0p = hb * HT;                        // padded-row base of tile
    const int c0p = wb * WTL;                       // padded-col base
    const unsigned short* xbn = xb + (size_t)n * 4 * HP * WP * 8;

    // ---- staging: 9 direct global->LDS 16B loads per thread, lane-linear dest ----
    #pragma unroll
    for (int it = 0; it < 9; ++it) {
        const int idx = it * 256 + t;
        const int w = idx % RCOLS;
        const int r = (idx / RCOLS) % RROWS;
        const int quad = idx / (RCOLS * RROWS);
        const size_t goff = (((size_t)(quad * HP + r0p + r)) * WP + (c0p + w)) * 8;
        gload_lds16(xbn + goff, &ldsx[(size_t)idx * 8]);
    }

    const int wave = t >> 6;
    const int lane = t & 63;
    const int l15 = lane & 15;      // A: m-row / B: pixel col / D: col
    const int quad4 = lane >> 4;    // A/B: k-group (8 ch) / D: och-quad
    const int mt = wave & 1;        // och tile (16 och)
    const int rbase = (wave >> 1) * 8;  // output-row base within tile

    const bf16x8* __restrict__ Wpt = (const bf16x8*)W2g;

    // preload A-frags for dx=0 (latency hidden under the barrier drain)
    bf16x8 A[2][9];
    #pragma unroll
    for (int dy = 0; dy < 9; dy++)
        A[0][dy] = Wpt[((mt * 81 + dy * 9 + 0) * 4 + quad4) * 16 + l15];

    __syncthreads();   // drains vmcnt -> all global_load_lds data visible in LDS

    f32x4 acc[8];
    #pragma unroll
    for (int i = 0; i < 8; i++) acc[i] = (f32x4){0.f, 0.f, 0.f, 0.f};

    const unsigned short* bptr = &ldsx[(size_t)(((quad4 * RROWS + rbase) * RCOLS) + l15) * 8];

    #pragma unroll
    for (int dx = 0; dx < 9; dx++) {
        const int cur = dx & 1, nxt = cur ^ 1;
        if (dx < 8) {
            #pragma unroll
            for (int dy = 0; dy < 9; dy++)
                A[nxt][dy] = Wpt[((mt * 81 + dy * 9 + (dx + 1)) * 4 + quad4) * 16 + l15];
        }
        __builtin_amdgcn_s_setprio(1);
        #pragma unroll
        for (int rr = 0; rr < 16; rr++) {           // lds row rel to rbase; out_r = rr - dy
            const bf16x8 bfrag = *(const bf16x8*)&bptr[(size_t)(rr * RCOLS + dx) * 8];
            #pragma unroll
            for (int dy = 0; dy < 9; dy++) {
                const int orr = rr - dy;
                if (orr >= 0 && orr < 8) {
                    acc[orr] = __builtin_amdgcn_mfma_f32_16x16x32_bf16(
                        A[cur][dy], bfrag, acc[orr], 0, 0, 0);
                }
            }
        }
        __builtin_amdgcn_s_setprio(0);
    }

    // ---- epilogue: D layout col = lane&15 (pixel), row = quad4*4 + reg (och) ----
    float* outn = out + (size_t)n * NOUT * H * W;
    float bb[4];
    #pragma unroll
    for (int reg = 0; reg < 4; reg++) bb[reg] = bias[mt * 16 + quad4 * 4 + reg];
    #pragma unroll
    for (int orr = 0; orr < 8; orr++) {
        const int row = hb * HT + rbase + orr;
        const int col = wb * WTL + l15;
        #pragma unroll
        for (int reg = 0; reg < 4; reg++) {
            const int och = mt * 16 + quad4 * 4 + reg;
            outn[((size_t)och * H + row) * W + col] = acc[orr][reg] + bb[reg];
        }
    }
}

// ---- Legacy conv kernel (fallback if workspace too small): the proven 190us path ----
__global__ __launch_bounds__(256, 4) void conv_kernel_legacy(
    const float* __restrict__ x, const unsigned short* __restrict__ W2g,
    const float* __restrict__ bias, float* __restrict__ out)
{
    __shared__ __align__(16) unsigned short ldsx[4 * RROWS * RCOLS * 8];

    const int t = threadIdx.x;
    const int bid = (blockIdx.x & 7) * 288 + (blockIdx.x >> 3);
    const int wb = bid % (W / WTL);
    const int hb = (bid / (W / WTL)) % (H / HT);
    const int n  = bid / ((W / WTL) * (H / HT));
    const int row0 = hb * HT - PADI;
    const int col0 = wb * WTL - PADI;
    const float* xn = x + (size_t)n * CIN * H * W;

    float v[9][8];
    #pragma unroll
    for (int it = 0; it < 9; ++it) {
        int idx = it * 256 + t;
        int w = idx % RCOLS;
        int r = (idx / RCOLS) % RROWS;
        int quad = idx / (RCOLS * RROWS);
        int row = row0 + r, col = col0 + w;
        #pragma unroll
        for (int k = 0; k < 8; k++) v[it][k] = 0.0f;
        if ((unsigned)row < (unsigned)H && (unsigned)col < (unsigned)W) {
            const float* p = xn + ((size_t)(quad * 8) * H + row) * W + col;
            #pragma unroll
            for (int k = 0; k < 8; k++) v[it][k] = p[(size_t)k * H * W];
        }
    }
    #pragma unroll
    for (int it = 0; it < 9; ++it) {
        int idx = it * 256 + t;
        unsigned int d[4];
        #pragma unroll
        for (int k = 0; k < 4; k++)
            d[k] = (unsigned int)f2bf(v[it][2 * k]) | ((unsigned int)f2bf(v[it][2 * k + 1]) << 16);
        *(uint4*)&ldsx[(size_t)idx * 8] = make_uint4(d[0], d[1], d[2], d[3]);
    }

    const int wave = t >> 6;
    const int lane = t & 63;
    const int l15 = lane & 15;
    const int quad4 = lane >> 4;
    const int mt = wave & 1;
    const int rbase = (wave >> 1) * 8;

    const bf16x8* __restrict__ Wpt = (const bf16x8*)W2g;

    bf16x8 A[2][9];
    #pragma unroll
    for (int dy = 0; dy < 9; dy++)
        A[0][dy] = Wpt[((mt * 81 + dy * 9 + 0) * 4 + quad4) * 16 + l15];

    __syncthreads();

    f32x4 acc[8];
    #pragma unroll
    for (int i = 0; i < 8; i++) acc[i] = (f32x4){0.f, 0.f, 0.f, 0.f};

    const unsigned short* bptr = &ldsx[(size_t)(((quad4 * RROWS + rbase) * RCOLS) + l15) * 8];

    #pragma unroll
    for (int dx = 0; dx < 9; dx++) {
        const int cur = dx & 1, nxt = cur ^ 1;
        if (dx < 8) {
            #pragma unroll
            for (int dy = 0; dy < 9; dy++)
                A[nxt][dy] = Wpt[((mt * 81 + dy * 9 + (dx + 1)) * 4 + quad4) * 16 + l15];
        }
        #pragma unroll
        for (int rr = 0; rr < 16; rr++) {
            const bf16x8 bfrag = *(const bf16x8*)&bptr[(size_t)(rr * RCOLS + dx) * 8];
            #pragma unroll
            for (int dy = 0; dy < 9; dy++) {
                const int orr = rr - dy;
                if (orr >= 0 && orr < 8) {
                    acc[orr] = __builtin_amdgcn_mfma_f32_16x16x32_bf16(
                        A[cur][dy], bfrag, acc[orr], 0, 0, 0);
                }
            }
        }
    }

    float* outn = out + (size_t)n * NOUT * H * W;
    float bb[4];
    #pragma unroll
    for (int reg = 0; reg < 4; reg++) bb[reg] = bias[mt * 16 + quad4 * 4 + reg];
    #pragma unroll
    for (int orr = 0; orr < 8; orr++) {
        const int row = hb * HT + rbase + orr;
        const int col = wb * WTL + l15;
        #pragma unroll
        for (int reg = 0; reg < 4; reg++) {
            const int och = mt * 16 + quad4 * 4 + reg;
            outn[((size_t)och * H + row) * W + col] = acc[orr][reg] + bb[reg];
        }
    }
}

extern "C" void kernel_launch(void* const* d_in, const int* in_sizes, int n_in,
                              void* d_out, int out_size, void* d_ws, size_t ws_size,
                              hipStream_t stream) {
    const float* x    = (const float*)d_in[0];
    const float* wp   = (const float*)d_in[1];   // (32,32,3)
    const float* bias = (const float*)d_in[2];   // (32,)
    float* out = (float*)d_out;

    unsigned short* W2g = (unsigned short*)d_ws;             // 165,888 B
    const size_t XB_OFF = 262144;                            // 256 KiB alignment pad
    const size_t XB_BYTES = (size_t)NB * 4 * HP * WP * 8 * 2; // 40,960,000 B
    unsigned short* xb = (unsigned short*)((char*)d_ws + XB_OFF);

    genw_kernel<<<NOUT * CIN, 128, 0, stream>>>(wp, W2g);

    const int blocks = NB * (H / HT) * (W / WTL);   // 2304

    if (ws_size >= XB_OFF + XB_BYTES) {
        const int xpad_blocks = (NB * 4 * HP * WP) / 256;    // 10,000
        xpad_kernel<<<xpad_blocks, 256, 0, stream>>>(x, xb);
        conv_kernel<<<blocks, 256, 0, stream>>>(xb, W2g, bias, out);
    } else {
        conv_kernel_legacy<<<blocks, 256, 0, stream>>>(x, W2g, bias, out);
    }
}